// Round 16
// baseline (52.172 us; speedup 1.0000x reference)
//
#include <hip/hip_runtime.h>

#define IMG_H 256
#define IMG_W 256
#define ROWS 16
#define NIMG 128
#define NWAVES (NIMG * 16 * 4)   // 8192 waves: img x 16 strips x 4 col-quarters

typedef const __attribute__((address_space(1))) float ga_f32;
typedef __attribute__((address_space(3))) float ls_f32;

// async global->LDS, 4B/lane, dest = uniform base + lane*4 (no VGPR round trip)
__device__ __forceinline__ void gll(const float* g, float* l) {
    __builtin_amdgcn_global_load_lds((ga_f32*)g, (ls_f32*)l, 4, 0, 0);
}

__device__ __forceinline__ float ssim1(float mu1, float mu2, float spp, float stt, float spt) {
    const float C1 = 1e-4f, C2 = 9e-4f;
    float mu1s = mu1 * mu1, mu2s = mu2 * mu2, mu12 = mu1 * mu2;
    float s1 = spp - mu1s, s2 = stt - mu2s, s12 = spt - mu12;
    float num = (2.f * mu12 + C1) * (2.f * s12 + C2);
    float den = (mu1s + mu2s + C1) * (s1 + s2 + C2);
    return num * __builtin_amdgcn_rcpf(den);
}

// H-first separable SSIM (R16). Series law: VALU duty tracks the VGPR
// occupancy bucket (R1: 44 regs -> 52%; R12: 84 -> 43%; R14+: >128 -> 32%).
// Target: <=64 VGPR (8 waves/SIMD). Register cuts vs R12 (84):
//  - staging via global_load_lds (6 calls/step): kills Pr/Tr/Hr + pack VALU
//  - exact-symmetric gaussian: g0..g3 only (window row3 is exactly symmetric)
//  - LDS layout [p 70 | t 70] x 2 buffers; double-buffer because VMEM->LDS
//    writes are NOT ordered vs same-wave ds_read (different pipes)
// Step: vmcnt(0) (waits PREV step's stage = 1 full step of cover) -> 14 b32
// reads -> stage next row into other buf -> H-conv -> V-conv+SSIM.
// Buffer parity via uniform pointer swap (SGPR); window slots static mod-7;
// rolled 2x7 steady loop (VGPR-proven shape). No barriers.
template<int ATOMIC>
__global__ __launch_bounds__(256) void ssim_main(
    const float* __restrict__ pred,
    const float* __restrict__ targ,
    const float* __restrict__ window,
    float* __restrict__ wsum)
{
    __shared__ float sbuf[4][2][140];   // [wave][buf][p:0..69 | t:70..139]

    const int lane = threadIdx.x & 63;
    const int wid  = threadIdx.x >> 6;
    const int gw   = blockIdx.x * 4 + wid;   // 0..8191
    const int n    = gw >> 6;                // image
    const int r    = gw & 63;
    const int r0   = (r >> 2) * ROWS;        // strip start row
    const int X0   = (r & 3) << 6;           // col quarter: 0/64/128/192

    // exact 1D gaussian from w2d row 3 (exactly symmetric): g0..g3
    float g0, g1, g2, g3;
    {
        float w0 = window[21], w1 = window[22], w2 = window[23], w3 = window[24],
              w4 = window[25], w5 = window[26], w6 = window[27];
        float inv = 1.f / (((w0 + w6) + (w1 + w5)) + ((w2 + w4) + w3));
        g0 = w0 * inv; g1 = w1 * inv; g2 = w2 * inv; g3 = w3 * inv;
    }

    const float* pimg = pred + (size_t)n * (IMG_H * IMG_W);
    const float* timg = targ + (size_t)n * (IMG_H * IMG_W);
    const int mo  = X0 + lane;                                // own column
    const int hco = (lane < 3) ? (X0 - 3 + lane) : (X0 + 61 + lane); // halo col (lanes 0..5)
    const bool lval = (X0 > 0);     // left halo cols in-bounds
    const bool rval = (X0 < 192);   // right halo cols in-bounds

    // mod-7 register window: 5 quantities x 7 slots (static idx)
    float Amu[7], Atu[7], App[7], Att[7], Apt[7];
    float acc = 0.f;

    float* br = &sbuf[wid][0][0];   // read buffer (uniform -> SGPR)
    float* bw = &sbuf[wid][1][0];   // stage buffer

    // pre-zero OOB-side halo slots (in-bounds staging never touches them)
    if (!lval && lane < 3) {
        br[lane] = 0.f; br[70 + lane] = 0.f;
        bw[lane] = 0.f; bw[70 + lane] = 0.f;
    }
    if (!rval && lane >= 3 && lane < 6) {
        br[64 + lane] = 0.f; br[134 + lane] = 0.f;
        bw[64 + lane] = 0.f; bw[134 + lane] = 0.f;
    }

// stage row J into buffer BW: p main [3..66], t main [73..136],
// halos p[0..2]/p[67..69], t[70..72]/t[137..139]. OOB row -> ds_write zeros.
#define STAGE(BW, J) { \
    const int j_ = (J); \
    if ((unsigned)j_ < (unsigned)IMG_H) { \
        const float* prow_ = pimg + j_ * IMG_W; \
        const float* trow_ = timg + j_ * IMG_W; \
        gll(prow_ + mo, (BW) + 3); \
        gll(trow_ + mo, (BW) + 73); \
        if (lval && lane < 3) { \
            gll(prow_ + hco, (BW)); \
            gll(trow_ + hco, (BW) + 70); \
        } \
        if (rval && lane >= 3 && lane < 6) { \
            gll(prow_ + hco, (BW) + 64); \
            gll(trow_ + hco, (BW) + 134); \
        } \
    } else { \
        (BW)[3 + lane] = 0.f; (BW)[73 + lane] = 0.f; \
        if (lane < 6) { \
            const int hx_ = (lane < 3) ? lane : (64 + lane); \
            (BW)[hx_] = 0.f; (BW)[hx_ + 70] = 0.f; \
        } \
    } }

#define VD(A_, U) ( fmaf(g0, A_[(U)%7] + A_[((U)+6)%7], \
    fmaf(g1, A_[((U)+1)%7] + A_[((U)+5)%7], \
    fmaf(g2, A_[((U)+2)%7] + A_[((U)+4)%7], g3 * A_[((U)+3)%7]))) )

#define OUTR(U) { \
    float m1 = VD(Amu,U), m2 = VD(Atu,U), pp = VD(App,U), \
          tt = VD(Att,U), pt = VD(Apt,U); \
    acc += ssim1(m1, m2, pp, tt, pt); }

// one step: wait prev stage -> read row j from br -> stage row JNEXT into bw
// -> symmetric H-conv into window slot -> optional output row -> swap bufs
#define STEPX(SLOT, JNEXT, HASOUT, U, DOSTAGE) { \
    asm volatile("s_waitcnt vmcnt(0)" ::: "memory"); \
    float p0 = br[lane],      p1 = br[lane + 1],  p2 = br[lane + 2], \
          p3 = br[lane + 3],  p4 = br[lane + 4],  p5 = br[lane + 5], \
          p6 = br[lane + 6]; \
    float t0 = br[lane + 70], t1 = br[lane + 71], t2 = br[lane + 72], \
          t3 = br[lane + 73], t4 = br[lane + 74], t5 = br[lane + 75], \
          t6 = br[lane + 76]; \
    if (DOSTAGE) { STAGE(bw, JNEXT) } \
    { \
        float a, b, c, d; \
        a = p0 + p6; b = p1 + p5; c = p2 + p4; \
        Amu[SLOT] = fmaf(g0, a, fmaf(g1, b, fmaf(g2, c, g3 * p3))); \
        a = t0 + t6; b = t1 + t5; c = t2 + t4; \
        Atu[SLOT] = fmaf(g0, a, fmaf(g1, b, fmaf(g2, c, g3 * t3))); \
        a = fmaf(p6, p6, p0 * p0); b = fmaf(p5, p5, p1 * p1); \
        c = fmaf(p4, p4, p2 * p2); d = p3 * p3; \
        App[SLOT] = fmaf(g0, a, fmaf(g1, b, fmaf(g2, c, g3 * d))); \
        a = fmaf(t6, t6, t0 * t0); b = fmaf(t5, t5, t1 * t1); \
        c = fmaf(t4, t4, t2 * t2); d = t3 * t3; \
        Att[SLOT] = fmaf(g0, a, fmaf(g1, b, fmaf(g2, c, g3 * d))); \
        a = fmaf(p6, t6, p0 * t0); b = fmaf(p5, t5, p1 * t1); \
        c = fmaf(p4, t4, p2 * t2); d = p3 * t3; \
        Apt[SLOT] = fmaf(g0, a, fmaf(g1, b, fmaf(g2, c, g3 * d))); \
    } \
    if (HASOUT) { OUTR(U) } \
    { float* swp_ = br; br = bw; bw = swp_; } }

    // prologue: stage first row into the first read buffer
    STAGE(br, r0 - 3)

    // rows r0-3 .. r0+2 -> slots 0..5 (no output yet)
    STEPX(0, r0 - 2, 0, 0, 1)
    STEPX(1, r0 - 1, 0, 0, 1)
    STEPX(2, r0,     0, 0, 1)
    STEPX(3, r0 + 1, 0, 0, 1)
    STEPX(4, r0 + 2, 0, 0, 1)
    STEPX(5, r0 + 3, 0, 0, 1)

    // steady: 2 x 7 steps, rows r0+3..r0+16, outputs r0..r0+13
#pragma unroll 1
    for (int jb = 0; jb < 2; ++jb) {
        const int base = r0 + 4 + jb * 7;   // stage row at body position 0
        STEPX(6, base,     1, 0, 1)
        STEPX(0, base + 1, 1, 1, 1)
        STEPX(1, base + 2, 1, 2, 1)
        STEPX(2, base + 3, 1, 3, 1)
        STEPX(3, base + 4, 1, 4, 1)
        STEPX(4, base + 5, 1, 5, 1)
        STEPX(5, base + 6, 1, 6, 1)
    }
    // tail: reads r0+17, r0+18 -> outputs r0+14, r0+15
    STEPX(6, r0 + 18, 1, 0, 1)
    STEPX(0, 0,       1, 1, 0)

#undef STAGE
#undef VD
#undef OUTR
#undef STEPX

    // wave reduce, one write (or atomic) per wave
#pragma unroll
    for (int off = 32; off > 0; off >>= 1)
        acc += __shfl_xor(acc, off, 64);
    if (lane == 0) {
        if (ATOMIC) atomicAdd(&wsum[0], acc);
        else        wsum[gw] = acc;
    }
}

// deterministic f64 tree-reduce of the 8192 per-wave partials
__global__ __launch_bounds__(256) void ssim_final_arr(
    const float* __restrict__ ws, float* __restrict__ out)
{
    __shared__ double sred[4];
    double sm = 0.0;
#pragma unroll
    for (int k = 0; k < NWAVES / 256; ++k)
        sm += (double)ws[threadIdx.x + k * 256];
#pragma unroll
    for (int off = 32; off > 0; off >>= 1)
        sm += __shfl_down(sm, off, 64);
    const int lane = threadIdx.x & 63, wid = threadIdx.x >> 6;
    if (lane == 0) sred[wid] = sm;
    __syncthreads();
    if (threadIdx.x == 0) {
        double tot = sred[0] + sred[1] + sred[2] + sred[3];
        out[0] = (float)(1.0 - tot * (1.0 / (128.0 * 256.0 * 256.0)));
    }
}

__global__ void ssim_final_sc(const float* __restrict__ ws, float* __restrict__ out)
{
    out[0] = 1.0f - ws[0] * (1.0f / (128.0f * 256.0f * 256.0f));
}

extern "C" void kernel_launch(void* const* d_in, const int* in_sizes, int n_in,
                              void* d_out, int out_size, void* d_ws, size_t ws_size,
                              hipStream_t stream)
{
    const float* pred   = (const float*)d_in[0];
    const float* targ   = (const float*)d_in[1];
    const float* window = (const float*)d_in[2];
    float* out = (float*)d_out;
    float* ws  = (float*)d_ws;

    if (ws_size >= NWAVES * sizeof(float)) {
        // every ws slot is written by the grid each call: no memset needed
        ssim_main<0><<<NWAVES / 4, 256, 0, stream>>>(pred, targ, window, ws);
        ssim_final_arr<<<1, 256, 0, stream>>>(ws, out);
    } else {
        hipMemsetAsync(ws, 0, sizeof(float), stream);
        ssim_main<1><<<NWAVES / 4, 256, 0, stream>>>(pred, targ, window, ws);
        ssim_final_sc<<<1, 1, 0, stream>>>(ws, out);
    }
    (void)in_sizes; (void)n_in; (void)out_size;
}

// Round 17
// 39.457 us; speedup vs baseline: 1.3222x; 1.3222x over previous
//
#include <hip/hip_runtime.h>

#define IMG_H 256
#define IMG_W 256
#define ROWS 16
#define NIMG 128
#define NWAVES (NIMG * 16 * 4)   // 8192 waves: img x 16 strips x 4 col-quarters

__device__ __forceinline__ float ssim1(float mu1, float mu2, float spp, float stt, float spt) {
    const float C1 = 1e-4f, C2 = 9e-4f;
    float mu1s = mu1 * mu1, mu2s = mu2 * mu2, mu12 = mu1 * mu2;
    float s1 = spp - mu1s, s2 = stt - mu2s, s12 = spt - mu12;
    float num = (2.f * mu12 + C1) * (2.f * s12 + C2);
    float den = (mu1s + mu2s + C1) * (s1 + s2 + C2);
    return num * __builtin_amdgcn_rcpf(den);
}

// H-first separable SSIM (R17 = R12 geometry x R1 allocator shape).
// Series law: VALU duty tracks the VGPR occupancy bucket (R1: 44->52%,
// R12: 84->43%, >128 -> ~32%). R1's 44 came from a SHIFTING window in a
// fully-ROLLED loop; R12+'s mod-7 static slots need a 7-wide unrolled body
// that inflates allocation to 84 regardless of staging path (R16 proved).
// So: shift-register window (30 movs/row -- +60cyc on ~220 busy) in ONE
// rolled 22-iter loop, targeting <=64 VGPR = 8 waves/SIMD. Geometry kept
// from R12: 1 col/thread, 64-col quarters, 4 waves/block with private LDS
// quadrants, no barriers (same-wave DS is in-order), 1-step global
// prefetch, float2-interleaved LDS row, exact-symmetric conv (R16 form).
template<int ATOMIC>
__global__ __launch_bounds__(256) void ssim_main(
    const float* __restrict__ pred,
    const float* __restrict__ targ,
    const float* __restrict__ window,
    float* __restrict__ wsum)
{
    __shared__ float2 sbuf[4][72];    // [wave][col c at idx c-X0+4]

    const int lane = threadIdx.x & 63;
    const int wid  = threadIdx.x >> 6;
    const int gw   = blockIdx.x * 4 + wid;   // 0..8191
    const int n    = gw >> 6;                // image
    const int r    = gw & 63;
    const int r0   = (r >> 2) * ROWS;        // strip start row
    const int X0   = (r & 3) << 6;           // col quarter: 0/64/128/192

    // exact 1D gaussian from w2d row 3 (exactly symmetric): g0..g3
    float g0, g1, g2, g3;
    {
        float w0 = window[21], w1 = window[22], w2 = window[23], w3 = window[24],
              w4 = window[25], w5 = window[26], w6 = window[27];
        float inv = 1.f / (((w0 + w6) + (w1 + w5)) + ((w2 + w4) + w3));
        g0 = w0 * inv; g1 = w1 * inv; g2 = w2 * inv; g3 = w3 * inv;
    }

    const float* pimg = pred + (size_t)n * (IMG_H * IMG_W);
    const float* timg = targ + (size_t)n * (IMG_H * IMG_W);
    const int mo = X0 + lane;         // own column

    // halo duty, lanes 0..5: left cols X0-3..X0-1 (idx 1..3),
    // right cols X0+64..X0+66 (idx 68..70)
    int hidx = 0, hcol = 0;
    if (lane < 3)      { hidx = lane + 1;  hcol = X0 - 3 + lane;  }
    else if (lane < 6) { hidx = lane + 65; hcol = X0 + 61 + lane; }
    const bool hv = (lane < 6) && ((unsigned)hcol < (unsigned)IMG_W);

    // shift-register window: 5 quantities x 7 rows, rows j-6..j at [0..6]
    float Amu[7], Atu[7], App[7], Att[7], Apt[7];
    float acc = 0.f;

    float Pr, Tr;        // global prefetch regs (own column)
    float2 Hr;           // global prefetch reg (halo col)

#define GLOAD(J) { \
    const int j_ = (J); \
    Pr = 0.f; Tr = 0.f; Hr = make_float2(0.f, 0.f); \
    if ((unsigned)j_ < (unsigned)IMG_H) { \
        const float* pr_ = pimg + j_ * IMG_W; \
        const float* tr_ = timg + j_ * IMG_W; \
        Pr = pr_[mo]; Tr = tr_[mo]; \
        if (hv) { Hr.x = pr_[hcol]; Hr.y = tr_[hcol]; } \
    } }

    // prologue: prefetch first halo row (r0-3)
    GLOAD(r0 - 3);

    float2* sw = sbuf[wid];

    // ONE rolled loop, 22 iterations: input rows r0-3 .. r0+18.
    // All register indices static; window shifts by one each iteration.
#pragma unroll 1
    for (int jj = 0; jj < 22; ++jj) {
        // stage row j = r0-3+jj (prefetched last iter; compiler inserts vmcnt)
        sw[lane + 4] = make_float2(Pr, Tr);
        if (lane < 6) sw[hidx] = Hr;

        // read own 7-col neighborhood (float2 = (p,t) per col)
        float2 q0 = sw[lane + 1], q1 = sw[lane + 2], q2 = sw[lane + 3];
        float2 q3 = sw[lane + 4], q4 = sw[lane + 5], q5 = sw[lane + 6];
        float2 q6 = sw[lane + 7];

        // prefetch next row (covered by the compute below; last iter's
        // target row r0+19 is wasted/OOB-guarded -- harmless)
        GLOAD(r0 - 2 + jj);

        // exact-symmetric horizontal 7-tap of the 5 quantities
        float hm, hu, hpp, htt, hpt;
        {
            float a, b, c;
            a = q0.x + q6.x; b = q1.x + q5.x; c = q2.x + q4.x;
            hm = fmaf(g0, a, fmaf(g1, b, fmaf(g2, c, g3 * q3.x)));
            a = q0.y + q6.y; b = q1.y + q5.y; c = q2.y + q4.y;
            hu = fmaf(g0, a, fmaf(g1, b, fmaf(g2, c, g3 * q3.y)));
            a = fmaf(q6.x, q6.x, q0.x * q0.x);
            b = fmaf(q5.x, q5.x, q1.x * q1.x);
            c = fmaf(q4.x, q4.x, q2.x * q2.x);
            hpp = fmaf(g0, a, fmaf(g1, b, fmaf(g2, c, g3 * (q3.x * q3.x))));
            a = fmaf(q6.y, q6.y, q0.y * q0.y);
            b = fmaf(q5.y, q5.y, q1.y * q1.y);
            c = fmaf(q4.y, q4.y, q2.y * q2.y);
            htt = fmaf(g0, a, fmaf(g1, b, fmaf(g2, c, g3 * (q3.y * q3.y))));
            a = fmaf(q6.x, q6.y, q0.x * q0.y);
            b = fmaf(q5.x, q5.y, q1.x * q1.y);
            c = fmaf(q4.x, q4.y, q2.x * q2.y);
            hpt = fmaf(g0, a, fmaf(g1, b, fmaf(g2, c, g3 * (q3.x * q3.y))));
        }

        // shift the 5 windows (static indices) and insert at [6]
        Amu[0] = Amu[1]; Amu[1] = Amu[2]; Amu[2] = Amu[3];
        Amu[3] = Amu[4]; Amu[4] = Amu[5]; Amu[5] = Amu[6]; Amu[6] = hm;
        Atu[0] = Atu[1]; Atu[1] = Atu[2]; Atu[2] = Atu[3];
        Atu[3] = Atu[4]; Atu[4] = Atu[5]; Atu[5] = Atu[6]; Atu[6] = hu;
        App[0] = App[1]; App[1] = App[2]; App[2] = App[3];
        App[3] = App[4]; App[4] = App[5]; App[5] = App[6]; App[6] = hpp;
        Att[0] = Att[1]; Att[1] = Att[2]; Att[2] = Att[3];
        Att[3] = Att[4]; Att[4] = Att[5]; Att[5] = Att[6]; Att[6] = htt;
        Apt[0] = Apt[1]; Apt[1] = Apt[2]; Apt[2] = Apt[3];
        Apt[3] = Apt[4]; Apt[4] = Apt[5]; Apt[5] = Apt[6]; Apt[6] = hpt;

        // output row j-3 once the window is full (wave-uniform branch)
        if (jj >= 6) {
            float m1 = fmaf(g0, Amu[0] + Amu[6], fmaf(g1, Amu[1] + Amu[5],
                       fmaf(g2, Amu[2] + Amu[4], g3 * Amu[3])));
            float m2 = fmaf(g0, Atu[0] + Atu[6], fmaf(g1, Atu[1] + Atu[5],
                       fmaf(g2, Atu[2] + Atu[4], g3 * Atu[3])));
            float pp = fmaf(g0, App[0] + App[6], fmaf(g1, App[1] + App[5],
                       fmaf(g2, App[2] + App[4], g3 * App[3])));
            float tt = fmaf(g0, Att[0] + Att[6], fmaf(g1, Att[1] + Att[5],
                       fmaf(g2, Att[2] + Att[4], g3 * Att[3])));
            float pt = fmaf(g0, Apt[0] + Apt[6], fmaf(g1, Apt[1] + Apt[5],
                       fmaf(g2, Apt[2] + Apt[4], g3 * Apt[3])));
            acc += ssim1(m1, m2, pp, tt, pt);
        }
    }

#undef GLOAD

    // wave reduce, one write (or atomic) per wave
#pragma unroll
    for (int off = 32; off > 0; off >>= 1)
        acc += __shfl_xor(acc, off, 64);
    if (lane == 0) {
        if (ATOMIC) atomicAdd(&wsum[0], acc);
        else        wsum[gw] = acc;
    }
}

// deterministic f64 tree-reduce of the 8192 per-wave partials
__global__ __launch_bounds__(256) void ssim_final_arr(
    const float* __restrict__ ws, float* __restrict__ out)
{
    __shared__ double sred[4];
    double sm = 0.0;
#pragma unroll
    for (int k = 0; k < NWAVES / 256; ++k)
        sm += (double)ws[threadIdx.x + k * 256];
#pragma unroll
    for (int off = 32; off > 0; off >>= 1)
        sm += __shfl_down(sm, off, 64);
    const int lane = threadIdx.x & 63, wid = threadIdx.x >> 6;
    if (lane == 0) sred[wid] = sm;
    __syncthreads();
    if (threadIdx.x == 0) {
        double tot = sred[0] + sred[1] + sred[2] + sred[3];
        out[0] = (float)(1.0 - tot * (1.0 / (128.0 * 256.0 * 256.0)));
    }
}

__global__ void ssim_final_sc(const float* __restrict__ ws, float* __restrict__ out)
{
    out[0] = 1.0f - ws[0] * (1.0f / (128.0f * 256.0f * 256.0f));
}

extern "C" void kernel_launch(void* const* d_in, const int* in_sizes, int n_in,
                              void* d_out, int out_size, void* d_ws, size_t ws_size,
                              hipStream_t stream)
{
    const float* pred   = (const float*)d_in[0];
    const float* targ   = (const float*)d_in[1];
    const float* window = (const float*)d_in[2];
    float* out = (float*)d_out;
    float* ws  = (float*)d_ws;

    if (ws_size >= NWAVES * sizeof(float)) {
        // every ws slot is written by the grid each call: no memset needed
        ssim_main<0><<<NWAVES / 4, 256, 0, stream>>>(pred, targ, window, ws);
        ssim_final_arr<<<1, 256, 0, stream>>>(ws, out);
    } else {
        hipMemsetAsync(ws, 0, sizeof(float), stream);
        ssim_main<1><<<NWAVES / 4, 256, 0, stream>>>(pred, targ, window, ws);
        ssim_final_sc<<<1, 1, 0, stream>>>(ws, out);
    }
    (void)in_sizes; (void)n_in; (void)out_size;
}

// Round 18
// 38.908 us; speedup vs baseline: 1.3409x; 1.0141x over previous
//
#include <hip/hip_runtime.h>

#define IMG_H 256
#define IMG_W 256
#define ROWS 32
#define NIMG 128
#define NWAVES (NIMG * 8 * 4)   // 4096 waves: img x 8 row-strips(32) x 4 col-quarters

__device__ __forceinline__ float ssim1(float mu1, float mu2, float spp, float stt, float spt) {
    const float C1 = 1e-4f, C2 = 9e-4f;
    float mu1s = mu1 * mu1, mu2s = mu2 * mu2, mu12 = mu1 * mu2;
    float s1 = spp - mu1s, s2 = stt - mu2s, s12 = spt - mu12;
    float num = (2.f * mu12 + C1) * (2.f * s12 + C2);
    float den = (mu1s + mu2s + C1) * (s1 + s2 + C2);
    return num * __builtin_amdgcn_rcpf(den);
}

// H-first separable SSIM (R18 = R17 with ROWS 16->32).
// R17 confirmed the series law causally: rolled loop + shift-register
// window -> 40 VGPR (8 waves/SIMD bucket) -> VALU duty 74%, 39.5us.
// Now mostly VALU-bound (~32us issue time). ROWS=32 cuts prologue
// amortization 22/16 -> 38/32 = -13.6% of ALL instruction traffic with a
// byte-identical loop body (unlike R15, whose ROWS bump inflated the
// mod-7 UNROLLED body -- the rolled body's VGPR shape is trip-count
// independent). Everything else identical to R17: 1 col/thread, 64-col
// quarters, 4 waves/block private LDS quadrants, no barriers, 1-step
// global prefetch, float2-interleaved LDS row, exact-symmetric conv.
template<int ATOMIC>
__global__ __launch_bounds__(256) void ssim_main(
    const float* __restrict__ pred,
    const float* __restrict__ targ,
    const float* __restrict__ window,
    float* __restrict__ wsum)
{
    __shared__ float2 sbuf[4][72];    // [wave][col c at idx c-X0+4]

    const int lane = threadIdx.x & 63;
    const int wid  = threadIdx.x >> 6;
    const int gw   = blockIdx.x * 4 + wid;   // 0..4095
    const int n    = gw >> 5;                // image
    const int r    = gw & 31;
    const int r0   = (r >> 2) * ROWS;        // strip start row (8 strips)
    const int X0   = (r & 3) << 6;           // col quarter: 0/64/128/192

    // exact 1D gaussian from w2d row 3 (exactly symmetric): g0..g3
    float g0, g1, g2, g3;
    {
        float w0 = window[21], w1 = window[22], w2 = window[23], w3 = window[24],
              w4 = window[25], w5 = window[26], w6 = window[27];
        float inv = 1.f / (((w0 + w6) + (w1 + w5)) + ((w2 + w4) + w3));
        g0 = w0 * inv; g1 = w1 * inv; g2 = w2 * inv; g3 = w3 * inv;
    }

    const float* pimg = pred + (size_t)n * (IMG_H * IMG_W);
    const float* timg = targ + (size_t)n * (IMG_H * IMG_W);
    const int mo = X0 + lane;         // own column

    // halo duty, lanes 0..5: left cols X0-3..X0-1 (idx 1..3),
    // right cols X0+64..X0+66 (idx 68..70)
    int hidx = 0, hcol = 0;
    if (lane < 3)      { hidx = lane + 1;  hcol = X0 - 3 + lane;  }
    else if (lane < 6) { hidx = lane + 65; hcol = X0 + 61 + lane; }
    const bool hv = (lane < 6) && ((unsigned)hcol < (unsigned)IMG_W);

    // shift-register window: 5 quantities x 7 rows, rows j-6..j at [0..6]
    float Amu[7], Atu[7], App[7], Att[7], Apt[7];
    float acc = 0.f;

    float Pr, Tr;        // global prefetch regs (own column)
    float2 Hr;           // global prefetch reg (halo col)

#define GLOAD(J) { \
    const int j_ = (J); \
    Pr = 0.f; Tr = 0.f; Hr = make_float2(0.f, 0.f); \
    if ((unsigned)j_ < (unsigned)IMG_H) { \
        const float* pr_ = pimg + j_ * IMG_W; \
        const float* tr_ = timg + j_ * IMG_W; \
        Pr = pr_[mo]; Tr = tr_[mo]; \
        if (hv) { Hr.x = pr_[hcol]; Hr.y = tr_[hcol]; } \
    } }

    // prologue: prefetch first halo row (r0-3)
    GLOAD(r0 - 3);

    float2* sw = sbuf[wid];

    // ONE rolled loop, 38 iterations: input rows r0-3 .. r0+34.
    // All register indices static; window shifts by one each iteration.
#pragma unroll 1
    for (int jj = 0; jj < ROWS + 6; ++jj) {
        // stage row j = r0-3+jj (prefetched last iter; compiler inserts vmcnt)
        sw[lane + 4] = make_float2(Pr, Tr);
        if (lane < 6) sw[hidx] = Hr;

        // read own 7-col neighborhood (float2 = (p,t) per col)
        float2 q0 = sw[lane + 1], q1 = sw[lane + 2], q2 = sw[lane + 3];
        float2 q3 = sw[lane + 4], q4 = sw[lane + 5], q5 = sw[lane + 6];
        float2 q6 = sw[lane + 7];

        // prefetch next row (covered by the compute below; trailing OOB
        // targets are guarded to zero -- harmless)
        GLOAD(r0 - 2 + jj);

        // exact-symmetric horizontal 7-tap of the 5 quantities
        float hm, hu, hpp, htt, hpt;
        {
            float a, b, c;
            a = q0.x + q6.x; b = q1.x + q5.x; c = q2.x + q4.x;
            hm = fmaf(g0, a, fmaf(g1, b, fmaf(g2, c, g3 * q3.x)));
            a = q0.y + q6.y; b = q1.y + q5.y; c = q2.y + q4.y;
            hu = fmaf(g0, a, fmaf(g1, b, fmaf(g2, c, g3 * q3.y)));
            a = fmaf(q6.x, q6.x, q0.x * q0.x);
            b = fmaf(q5.x, q5.x, q1.x * q1.x);
            c = fmaf(q4.x, q4.x, q2.x * q2.x);
            hpp = fmaf(g0, a, fmaf(g1, b, fmaf(g2, c, g3 * (q3.x * q3.x))));
            a = fmaf(q6.y, q6.y, q0.y * q0.y);
            b = fmaf(q5.y, q5.y, q1.y * q1.y);
            c = fmaf(q4.y, q4.y, q2.y * q2.y);
            htt = fmaf(g0, a, fmaf(g1, b, fmaf(g2, c, g3 * (q3.y * q3.y))));
            a = fmaf(q6.x, q6.y, q0.x * q0.y);
            b = fmaf(q5.x, q5.y, q1.x * q1.y);
            c = fmaf(q4.x, q4.y, q2.x * q2.y);
            hpt = fmaf(g0, a, fmaf(g1, b, fmaf(g2, c, g3 * (q3.x * q3.y))));
        }

        // shift the 5 windows (static indices) and insert at [6]
        Amu[0] = Amu[1]; Amu[1] = Amu[2]; Amu[2] = Amu[3];
        Amu[3] = Amu[4]; Amu[4] = Amu[5]; Amu[5] = Amu[6]; Amu[6] = hm;
        Atu[0] = Atu[1]; Atu[1] = Atu[2]; Atu[2] = Atu[3];
        Atu[3] = Atu[4]; Atu[4] = Atu[5]; Atu[5] = Atu[6]; Atu[6] = hu;
        App[0] = App[1]; App[1] = App[2]; App[2] = App[3];
        App[3] = App[4]; App[4] = App[5]; App[5] = App[6]; App[6] = hpp;
        Att[0] = Att[1]; Att[1] = Att[2]; Att[2] = Att[3];
        Att[3] = Att[4]; Att[4] = Att[5]; Att[5] = Att[6]; Att[6] = htt;
        Apt[0] = Apt[1]; Apt[1] = Apt[2]; Apt[2] = Apt[3];
        Apt[3] = Apt[4]; Apt[4] = Apt[5]; Apt[5] = Apt[6]; Apt[6] = hpt;

        // output row j-3 once the window is full (wave-uniform branch)
        if (jj >= 6) {
            float m1 = fmaf(g0, Amu[0] + Amu[6], fmaf(g1, Amu[1] + Amu[5],
                       fmaf(g2, Amu[2] + Amu[4], g3 * Amu[3])));
            float m2 = fmaf(g0, Atu[0] + Atu[6], fmaf(g1, Atu[1] + Atu[5],
                       fmaf(g2, Atu[2] + Atu[4], g3 * Atu[3])));
            float pp = fmaf(g0, App[0] + App[6], fmaf(g1, App[1] + App[5],
                       fmaf(g2, App[2] + App[4], g3 * App[3])));
            float tt = fmaf(g0, Att[0] + Att[6], fmaf(g1, Att[1] + Att[5],
                       fmaf(g2, Att[2] + Att[4], g3 * Att[3])));
            float pt = fmaf(g0, Apt[0] + Apt[6], fmaf(g1, Apt[1] + Apt[5],
                       fmaf(g2, Apt[2] + Apt[4], g3 * Apt[3])));
            acc += ssim1(m1, m2, pp, tt, pt);
        }
    }

#undef GLOAD

    // wave reduce, one write (or atomic) per wave
#pragma unroll
    for (int off = 32; off > 0; off >>= 1)
        acc += __shfl_xor(acc, off, 64);
    if (lane == 0) {
        if (ATOMIC) atomicAdd(&wsum[0], acc);
        else        wsum[gw] = acc;
    }
}

// deterministic f64 tree-reduce of the 4096 per-wave partials
__global__ __launch_bounds__(256) void ssim_final_arr(
    const float* __restrict__ ws, float* __restrict__ out)
{
    __shared__ double sred[4];
    double sm = 0.0;
#pragma unroll
    for (int k = 0; k < NWAVES / 256; ++k)
        sm += (double)ws[threadIdx.x + k * 256];
#pragma unroll
    for (int off = 32; off > 0; off >>= 1)
        sm += __shfl_down(sm, off, 64);
    const int lane = threadIdx.x & 63, wid = threadIdx.x >> 6;
    if (lane == 0) sred[wid] = sm;
    __syncthreads();
    if (threadIdx.x == 0) {
        double tot = sred[0] + sred[1] + sred[2] + sred[3];
        out[0] = (float)(1.0 - tot * (1.0 / (128.0 * 256.0 * 256.0)));
    }
}

__global__ void ssim_final_sc(const float* __restrict__ ws, float* __restrict__ out)
{
    out[0] = 1.0f - ws[0] * (1.0f / (128.0f * 256.0f * 256.0f));
}

extern "C" void kernel_launch(void* const* d_in, const int* in_sizes, int n_in,
                              void* d_out, int out_size, void* d_ws, size_t ws_size,
                              hipStream_t stream)
{
    const float* pred   = (const float*)d_in[0];
    const float* targ   = (const float*)d_in[1];
    const float* window = (const float*)d_in[2];
    float* out = (float*)d_out;
    float* ws  = (float*)d_ws;

    if (ws_size >= NWAVES * sizeof(float)) {
        // every ws slot is written by the grid each call: no memset needed
        ssim_main<0><<<NWAVES / 4, 256, 0, stream>>>(pred, targ, window, ws);
        ssim_final_arr<<<1, 256, 0, stream>>>(ws, out);
    } else {
        hipMemsetAsync(ws, 0, sizeof(float), stream);
        ssim_main<1><<<NWAVES / 4, 256, 0, stream>>>(pred, targ, window, ws);
        ssim_final_sc<<<1, 1, 0, stream>>>(ws, out);
    }
    (void)in_sizes; (void)n_in; (void)out_size;
}

// Round 19
// 37.969 us; speedup vs baseline: 1.3741x; 1.0247x over previous
//
#include <hip/hip_runtime.h>

#define IMG_H 256
#define IMG_W 256
#define ROWS 32
#define NIMG 128
#define NWAVES (NIMG * 8 * 4)   // 4096 waves: img x 8 row-strips(32) x 4 col-quarters

typedef __attribute__((ext_vector_type(2))) float v2f;

__device__ __forceinline__ v2f vfma(v2f a, v2f b, v2f c) {
    return __builtin_elementwise_fma(a, b, c);
}
__device__ __forceinline__ v2f sp(float x) { v2f r; r.x = x; r.y = x; return r; }

__device__ __forceinline__ float ssim1(float mu1, float mu2, float spp, float stt, float spt) {
    const float C1 = 1e-4f, C2 = 9e-4f;
    float mu1s = mu1 * mu1, mu2s = mu2 * mu2, mu12 = mu1 * mu2;
    float s1 = spp - mu1s, s2 = stt - mu2s, s12 = spt - mu12;
    float num = (2.f * mu12 + C1) * (2.f * s12 + C2);
    float den = (mu1s + mu2s + C1) * (s1 + s2 + C2);
    return num * __builtin_amdgcn_rcpf(den);
}

// H-first separable SSIM (R19 = R18 + PACKED FP32 math).
// R18: 27us of pure VALU-issue at 40 VGPR -- issue-bound. CDNA4 has
// full-rate v_pk_{fma,add,mul}_f32 (1 instr = 2 fp32 lane-ops), and our
// quantities pair naturally: (mu_p,mu_t) and (p^2,t^2) have identical conv
// structure on (p,t) = float2. ext_vector_type(2) arithmetic emits
// <2 x float> IR -> v_pk_* on gfx950. Only the p*t quantity stays scalar.
// Per-step issues ~150 -> ~100. Window: 2 v2f arrays + 1 scalar (same 35
// VGPR footprint). Everything else byte-identical to R18 (rolled 38-iter
// loop, shift-register window, 1 col/thread, private LDS quadrants, no
// barriers, 1-step global prefetch, exact-symmetric taps).
template<int ATOMIC>
__global__ __launch_bounds__(256) void ssim_main(
    const float* __restrict__ pred,
    const float* __restrict__ targ,
    const float* __restrict__ window,
    float* __restrict__ wsum)
{
    __shared__ v2f sbuf[4][72];    // [wave][col c at idx c-X0+4] = (p,t)

    const int lane = threadIdx.x & 63;
    const int wid  = threadIdx.x >> 6;
    const int gw   = blockIdx.x * 4 + wid;   // 0..4095
    const int n    = gw >> 5;                // image
    const int r    = gw & 31;
    const int r0   = (r >> 2) * ROWS;        // strip start row (8 strips)
    const int X0   = (r & 3) << 6;           // col quarter: 0/64/128/192

    // exact 1D gaussian from w2d row 3 (exactly symmetric): g0..g3
    float g0, g1, g2, g3;
    {
        float w0 = window[21], w1 = window[22], w2 = window[23], w3 = window[24],
              w4 = window[25], w5 = window[26], w6 = window[27];
        float inv = 1.f / (((w0 + w6) + (w1 + w5)) + ((w2 + w4) + w3));
        g0 = w0 * inv; g1 = w1 * inv; g2 = w2 * inv; g3 = w3 * inv;
    }

    const float* pimg = pred + (size_t)n * (IMG_H * IMG_W);
    const float* timg = targ + (size_t)n * (IMG_H * IMG_W);
    const int mo = X0 + lane;         // own column

    // halo duty, lanes 0..5: left cols X0-3..X0-1 (idx 1..3),
    // right cols X0+64..X0+66 (idx 68..70)
    int hidx = 0, hcol = 0;
    if (lane < 3)      { hidx = lane + 1;  hcol = X0 - 3 + lane;  }
    else if (lane < 6) { hidx = lane + 65; hcol = X0 + 61 + lane; }
    const bool hv = (lane < 6) && ((unsigned)hcol < (unsigned)IMG_W);

    // shift-register windows: rows j-6..j at [0..6]
    v2f  Wmu[7];   // (H-conv of p, H-conv of t)
    v2f  Wsq[7];   // (H-conv of p^2, H-conv of t^2)
    float Wpt[7];  // H-conv of p*t
    float acc = 0.f;

    float Pr, Tr;        // global prefetch regs (own column)
    v2f Hr;              // global prefetch reg (halo col)

#define GLOAD(J) { \
    const int j_ = (J); \
    Pr = 0.f; Tr = 0.f; Hr.x = 0.f; Hr.y = 0.f; \
    if ((unsigned)j_ < (unsigned)IMG_H) { \
        const float* pr_ = pimg + j_ * IMG_W; \
        const float* tr_ = timg + j_ * IMG_W; \
        Pr = pr_[mo]; Tr = tr_[mo]; \
        if (hv) { Hr.x = pr_[hcol]; Hr.y = tr_[hcol]; } \
    } }

    // prologue: prefetch first halo row (r0-3)
    GLOAD(r0 - 3);

    v2f* sw = sbuf[wid];

    // ONE rolled loop, 38 iterations: input rows r0-3 .. r0+34.
#pragma unroll 1
    for (int jj = 0; jj < ROWS + 6; ++jj) {
        // stage row j = r0-3+jj (prefetched last iter)
        v2f st; st.x = Pr; st.y = Tr;
        sw[lane + 4] = st;
        if (lane < 6) sw[hidx] = Hr;

        // read own 7-col neighborhood ((p,t) per col)
        v2f q0 = sw[lane + 1], q1 = sw[lane + 2], q2 = sw[lane + 3];
        v2f q3 = sw[lane + 4], q4 = sw[lane + 5], q5 = sw[lane + 6];
        v2f q6 = sw[lane + 7];

        // prefetch next row (covered by the compute below; trailing OOB
        // targets are guarded to zero -- harmless)
        GLOAD(r0 - 2 + jj);

        // exact-symmetric horizontal 7-tap, packed where pairable
        v2f hmu, hsq;
        float hpt;
        {
            // (mu_p, mu_t): packed
            v2f a = q0 + q6, b = q1 + q5, c = q2 + q4;
            hmu = vfma(sp(g0), a, vfma(sp(g1), b, vfma(sp(g2), c, sp(g3) * q3)));
            // (p^2, t^2): packed
            v2f a2 = vfma(q6, q6, q0 * q0);
            v2f b2 = vfma(q5, q5, q1 * q1);
            v2f c2 = vfma(q4, q4, q2 * q2);
            v2f d2 = q3 * q3;
            hsq = vfma(sp(g0), a2, vfma(sp(g1), b2, vfma(sp(g2), c2, sp(g3) * d2)));
            // p*t: scalar
            float ap = fmaf(q6.x, q6.y, q0.x * q0.y);
            float bp = fmaf(q5.x, q5.y, q1.x * q1.y);
            float cp = fmaf(q4.x, q4.y, q2.x * q2.y);
            hpt = fmaf(g0, ap, fmaf(g1, bp, fmaf(g2, cp, g3 * (q3.x * q3.y))));
        }

        // shift windows (static indices) and insert at [6]
        Wmu[0] = Wmu[1]; Wmu[1] = Wmu[2]; Wmu[2] = Wmu[3];
        Wmu[3] = Wmu[4]; Wmu[4] = Wmu[5]; Wmu[5] = Wmu[6]; Wmu[6] = hmu;
        Wsq[0] = Wsq[1]; Wsq[1] = Wsq[2]; Wsq[2] = Wsq[3];
        Wsq[3] = Wsq[4]; Wsq[4] = Wsq[5]; Wsq[5] = Wsq[6]; Wsq[6] = hsq;
        Wpt[0] = Wpt[1]; Wpt[1] = Wpt[2]; Wpt[2] = Wpt[3];
        Wpt[3] = Wpt[4]; Wpt[4] = Wpt[5]; Wpt[5] = Wpt[6]; Wpt[6] = hpt;

        // output row j-3 once the window is full (wave-uniform branch)
        if (jj >= 6) {
            v2f m12 = vfma(sp(g0), Wmu[0] + Wmu[6],
                      vfma(sp(g1), Wmu[1] + Wmu[5],
                      vfma(sp(g2), Wmu[2] + Wmu[4], sp(g3) * Wmu[3])));
            v2f s12 = vfma(sp(g0), Wsq[0] + Wsq[6],
                      vfma(sp(g1), Wsq[1] + Wsq[5],
                      vfma(sp(g2), Wsq[2] + Wsq[4], sp(g3) * Wsq[3])));
            float pt = fmaf(g0, Wpt[0] + Wpt[6], fmaf(g1, Wpt[1] + Wpt[5],
                       fmaf(g2, Wpt[2] + Wpt[4], g3 * Wpt[3])));
            acc += ssim1(m12.x, m12.y, s12.x, s12.y, pt);
        }
    }

#undef GLOAD

    // wave reduce, one write (or atomic) per wave
#pragma unroll
    for (int off = 32; off > 0; off >>= 1)
        acc += __shfl_xor(acc, off, 64);
    if (lane == 0) {
        if (ATOMIC) atomicAdd(&wsum[0], acc);
        else        wsum[gw] = acc;
    }
}

// deterministic f64 tree-reduce of the 4096 per-wave partials
__global__ __launch_bounds__(256) void ssim_final_arr(
    const float* __restrict__ ws, float* __restrict__ out)
{
    __shared__ double sred[4];
    double sm = 0.0;
#pragma unroll
    for (int k = 0; k < NWAVES / 256; ++k)
        sm += (double)ws[threadIdx.x + k * 256];
#pragma unroll
    for (int off = 32; off > 0; off >>= 1)
        sm += __shfl_down(sm, off, 64);
    const int lane = threadIdx.x & 63, wid = threadIdx.x >> 6;
    if (lane == 0) sred[wid] = sm;
    __syncthreads();
    if (threadIdx.x == 0) {
        double tot = sred[0] + sred[1] + sred[2] + sred[3];
        out[0] = (float)(1.0 - tot * (1.0 / (128.0 * 256.0 * 256.0)));
    }
}

__global__ void ssim_final_sc(const float* __restrict__ ws, float* __restrict__ out)
{
    out[0] = 1.0f - ws[0] * (1.0f / (128.0f * 256.0f * 256.0f));
}

extern "C" void kernel_launch(void* const* d_in, const int* in_sizes, int n_in,
                              void* d_out, int out_size, void* d_ws, size_t ws_size,
                              hipStream_t stream)
{
    const float* pred   = (const float*)d_in[0];
    const float* targ   = (const float*)d_in[1];
    const float* window = (const float*)d_in[2];
    float* out = (float*)d_out;
    float* ws  = (float*)d_ws;

    if (ws_size >= NWAVES * sizeof(float)) {
        // every ws slot is written by the grid each call: no memset needed
        ssim_main<0><<<NWAVES / 4, 256, 0, stream>>>(pred, targ, window, ws);
        ssim_final_arr<<<1, 256, 0, stream>>>(ws, out);
    } else {
        hipMemsetAsync(ws, 0, sizeof(float), stream);
        ssim_main<1><<<NWAVES / 4, 256, 0, stream>>>(pred, targ, window, ws);
        ssim_final_sc<<<1, 1, 0, stream>>>(ws, out);
    }
    (void)in_sizes; (void)n_in; (void)out_size;
}

// Round 20
// 36.436 us; speedup vs baseline: 1.4319x; 1.0421x over previous
//
#include <hip/hip_runtime.h>

#define IMG_H 256
#define IMG_W 256
#define ROWS 32
#define NIMG 128
#define NWAVES (NIMG * 8 * 4)   // 4096 waves: img x 8 row-strips(32) x 4 col-quarters

typedef __attribute__((ext_vector_type(2))) float v2f;

__device__ __forceinline__ v2f vfma(v2f a, v2f b, v2f c) {
    return __builtin_elementwise_fma(a, b, c);
}
__device__ __forceinline__ v2f sp(float x) { v2f r; r.x = x; r.y = x; return r; }

__device__ __forceinline__ float ssim1(float mu1, float mu2, float spp, float stt, float spt) {
    const float C1 = 1e-4f, C2 = 9e-4f;
    float mu1s = mu1 * mu1, mu2s = mu2 * mu2, mu12 = mu1 * mu2;
    float s1 = spp - mu1s, s2 = stt - mu2s, s12 = spt - mu12;
    float num = (2.f * mu12 + C1) * (2.f * s12 + C2);
    float den = (mu1s + mu2s + C1) * (s1 + s2 + C2);
    return num * __builtin_amdgcn_rcpf(den);
}

// H-first separable SSIM (R20 = R19 + PAIR PROCESSING, shift-by-2).
// R19 post-mortem: shift-register movs were 30/row = ~29% of VALU issues.
// Pair scheme: per iteration process rows (j, j+1); outputs j-3 (W[0..5]
// + hA) and j-2 (W[1..5] + hA + hB) BEFORE the shift; then W[i]=W[i+2]
// (4 movs) + 2 inserts -> 30 shift-instrs per PAIR (was 60), and loop
// overhead halves. Two static prefetch reg sets (A/B), each loaded in its
// own half, ~full-half cover. Same proven pieces: rolled loop (19 pairs),
// packed v2f math, 1 col/thread, private LDS quadrants, single-buffer
// in-order same-wave DS, no barriers, exact-symmetric taps.
template<int ATOMIC>
__global__ __launch_bounds__(256) void ssim_main(
    const float* __restrict__ pred,
    const float* __restrict__ targ,
    const float* __restrict__ window,
    float* __restrict__ wsum)
{
    __shared__ v2f sbuf[4][72];    // [wave][col c at idx c-X0+4] = (p,t)

    const int lane = threadIdx.x & 63;
    const int wid  = threadIdx.x >> 6;
    const int gw   = blockIdx.x * 4 + wid;   // 0..4095
    const int n    = gw >> 5;                // image
    const int r    = gw & 31;
    const int r0   = (r >> 2) * ROWS;        // strip start row (8 strips)
    const int X0   = (r & 3) << 6;           // col quarter: 0/64/128/192

    // exact 1D gaussian from w2d row 3 (exactly symmetric): g0..g3
    float g0, g1, g2, g3;
    {
        float w0 = window[21], w1 = window[22], w2 = window[23], w3 = window[24],
              w4 = window[25], w5 = window[26], w6 = window[27];
        float inv = 1.f / (((w0 + w6) + (w1 + w5)) + ((w2 + w4) + w3));
        g0 = w0 * inv; g1 = w1 * inv; g2 = w2 * inv; g3 = w3 * inv;
    }

    const float* pimg = pred + (size_t)n * (IMG_H * IMG_W);
    const float* timg = targ + (size_t)n * (IMG_H * IMG_W);
    const int mo = X0 + lane;         // own column

    // halo duty, lanes 0..5: left cols X0-3..X0-1 (idx 1..3),
    // right cols X0+64..X0+66 (idx 68..70)
    int hidx = 0, hcol = 0;
    if (lane < 3)      { hidx = lane + 1;  hcol = X0 - 3 + lane;  }
    else if (lane < 6) { hidx = lane + 65; hcol = X0 + 61 + lane; }
    const bool hv = (lane < 6) && ((unsigned)hcol < (unsigned)IMG_W);

    // 6-slot window: W[i] = H(row j-6+i) at pair start (j = first row of pair)
    v2f  Wmu[6], Wsq[6];
    float Wpt[6];
#pragma unroll
    for (int i = 0; i < 6; ++i) { Wmu[i] = sp(0.f); Wsq[i] = sp(0.f); Wpt[i] = 0.f; }
    float acc = 0.f;

    float PrA, TrA, PrB, TrB;   // two static prefetch generations
    v2f HrA, HrB;

#define GLOADX(J, PR, TR, HR) { \
    const int j_ = (J); \
    PR = 0.f; TR = 0.f; HR.x = 0.f; HR.y = 0.f; \
    if ((unsigned)j_ < (unsigned)IMG_H) { \
        const float* pr_ = pimg + j_ * IMG_W; \
        const float* tr_ = timg + j_ * IMG_W; \
        PR = pr_[mo]; TR = tr_[mo]; \
        if (hv) { HR.x = pr_[hcol]; HR.y = tr_[hcol]; } \
    } }

// stage (PR,TR,HR) as current LDS row, read 7-col neighborhood, H-conv
#define HALF(PR, TR, HR, HMU, HSQ, HPT) { \
    { v2f st_; st_.x = PR; st_.y = TR; sw[lane + 4] = st_; } \
    if (lane < 6) sw[hidx] = HR; \
    v2f q0 = sw[lane + 1], q1 = sw[lane + 2], q2 = sw[lane + 3]; \
    v2f q3 = sw[lane + 4], q4 = sw[lane + 5], q5 = sw[lane + 6]; \
    v2f q6 = sw[lane + 7]; \
    { \
        v2f a = q0 + q6, b = q1 + q5, c = q2 + q4; \
        HMU = vfma(sp(g0), a, vfma(sp(g1), b, vfma(sp(g2), c, sp(g3) * q3))); \
        v2f a2 = vfma(q6, q6, q0 * q0); \
        v2f b2 = vfma(q5, q5, q1 * q1); \
        v2f c2 = vfma(q4, q4, q2 * q2); \
        v2f d2 = q3 * q3; \
        HSQ = vfma(sp(g0), a2, vfma(sp(g1), b2, vfma(sp(g2), c2, sp(g3) * d2))); \
        float ap = fmaf(q6.x, q6.y, q0.x * q0.y); \
        float bp = fmaf(q5.x, q5.y, q1.x * q1.y); \
        float cp = fmaf(q4.x, q4.y, q2.x * q2.y); \
        HPT = fmaf(g0, ap, fmaf(g1, bp, fmaf(g2, cp, g3 * (q3.x * q3.y)))); \
    } }

    // prologue: prefetch rows r0-3 (A) and r0-2 (B)
    GLOADX(r0 - 3, PrA, TrA, HrA)
    GLOADX(r0 - 2, PrB, TrB, HrB)

    v2f* sw = sbuf[wid];

    v2f hmuA, hsqA, hmuB, hsqB;
    float hptA, hptB;

    // 19 pairs: rows (r0-3+2p, r0-2+2p); pairs 0..2 prologue (no output)
#pragma unroll 1
    for (int pp = 0; pp < 19; ++pp) {
        const int j = r0 - 3 + 2 * pp;

        // half A: row j; then prefetch row j+2 into the A set
        HALF(PrA, TrA, HrA, hmuA, hsqA, hptA)
        GLOADX(j + 2, PrA, TrA, HrA)

        // half B: row j+1; then prefetch row j+3 into the B set
        HALF(PrB, TrB, HrB, hmuB, hsqB, hptB)
        GLOADX(j + 3, PrB, TrB, HrB)

        if (pp >= 3) {
            // output row j-3: H rows j-6..j = W[0..5] + hA
            {
                v2f m12 = vfma(sp(g0), Wmu[0] + hmuA,
                          vfma(sp(g1), Wmu[1] + Wmu[5],
                          vfma(sp(g2), Wmu[2] + Wmu[4], sp(g3) * Wmu[3])));
                v2f s12 = vfma(sp(g0), Wsq[0] + hsqA,
                          vfma(sp(g1), Wsq[1] + Wsq[5],
                          vfma(sp(g2), Wsq[2] + Wsq[4], sp(g3) * Wsq[3])));
                float pt = fmaf(g0, Wpt[0] + hptA, fmaf(g1, Wpt[1] + Wpt[5],
                           fmaf(g2, Wpt[2] + Wpt[4], g3 * Wpt[3])));
                acc += ssim1(m12.x, m12.y, s12.x, s12.y, pt);
            }
            // output row j-2: H rows j-5..j+1 = W[1..5] + hA + hB
            {
                v2f m12 = vfma(sp(g0), Wmu[1] + hmuB,
                          vfma(sp(g1), Wmu[2] + hmuA,
                          vfma(sp(g2), Wmu[3] + Wmu[5], sp(g3) * Wmu[4])));
                v2f s12 = vfma(sp(g0), Wsq[1] + hsqB,
                          vfma(sp(g1), Wsq[2] + hsqA,
                          vfma(sp(g2), Wsq[3] + Wsq[5], sp(g3) * Wsq[4])));
                float pt = fmaf(g0, Wpt[1] + hptB, fmaf(g1, Wpt[2] + hptA,
                           fmaf(g2, Wpt[3] + Wpt[5], g3 * Wpt[4])));
                acc += ssim1(m12.x, m12.y, s12.x, s12.y, pt);
            }
        }

        // shift by 2 and insert the fresh pair (static indices)
        Wmu[0] = Wmu[2]; Wmu[1] = Wmu[3]; Wmu[2] = Wmu[4]; Wmu[3] = Wmu[5];
        Wmu[4] = hmuA;   Wmu[5] = hmuB;
        Wsq[0] = Wsq[2]; Wsq[1] = Wsq[3]; Wsq[2] = Wsq[4]; Wsq[3] = Wsq[5];
        Wsq[4] = hsqA;   Wsq[5] = hsqB;
        Wpt[0] = Wpt[2]; Wpt[1] = Wpt[3]; Wpt[2] = Wpt[4]; Wpt[3] = Wpt[5];
        Wpt[4] = hptA;   Wpt[5] = hptB;
    }

#undef GLOADX
#undef HALF

    // wave reduce, one write (or atomic) per wave
#pragma unroll
    for (int off = 32; off > 0; off >>= 1)
        acc += __shfl_xor(acc, off, 64);
    if (lane == 0) {
        if (ATOMIC) atomicAdd(&wsum[0], acc);
        else        wsum[gw] = acc;
    }
}

// deterministic f64 tree-reduce of the 4096 per-wave partials
__global__ __launch_bounds__(256) void ssim_final_arr(
    const float* __restrict__ ws, float* __restrict__ out)
{
    __shared__ double sred[4];
    double sm = 0.0;
#pragma unroll
    for (int k = 0; k < NWAVES / 256; ++k)
        sm += (double)ws[threadIdx.x + k * 256];
#pragma unroll
    for (int off = 32; off > 0; off >>= 1)
        sm += __shfl_down(sm, off, 64);
    const int lane = threadIdx.x & 63, wid = threadIdx.x >> 6;
    if (lane == 0) sred[wid] = sm;
    __syncthreads();
    if (threadIdx.x == 0) {
        double tot = sred[0] + sred[1] + sred[2] + sred[3];
        out[0] = (float)(1.0 - tot * (1.0 / (128.0 * 256.0 * 256.0)));
    }
}

__global__ void ssim_final_sc(const float* __restrict__ ws, float* __restrict__ out)
{
    out[0] = 1.0f - ws[0] * (1.0f / (128.0f * 256.0f * 256.0f));
}

extern "C" void kernel_launch(void* const* d_in, const int* in_sizes, int n_in,
                              void* d_out, int out_size, void* d_ws, size_t ws_size,
                              hipStream_t stream)
{
    const float* pred   = (const float*)d_in[0];
    const float* targ   = (const float*)d_in[1];
    const float* window = (const float*)d_in[2];
    float* out = (float*)d_out;
    float* ws  = (float*)d_ws;

    if (ws_size >= NWAVES * sizeof(float)) {
        // every ws slot is written by the grid each call: no memset needed
        ssim_main<0><<<NWAVES / 4, 256, 0, stream>>>(pred, targ, window, ws);
        ssim_final_arr<<<1, 256, 0, stream>>>(ws, out);
    } else {
        hipMemsetAsync(ws, 0, sizeof(float), stream);
        ssim_main<1><<<NWAVES / 4, 256, 0, stream>>>(pred, targ, window, ws);
        ssim_final_sc<<<1, 1, 0, stream>>>(ws, out);
    }
    (void)in_sizes; (void)n_in; (void)out_size;
}

// Round 24
// 36.029 us; speedup vs baseline: 1.4481x; 1.0113x over previous
//
#include <hip/hip_runtime.h>

#define IMG_H 256
#define IMG_W 256
#define ROWS 32
#define NIMG 128
#define NWAVES (NIMG * 8 * 4)   // 4096 waves: img x 8 row-strips(32) x 4 col-quarters

typedef __attribute__((ext_vector_type(2))) float v2f;

__device__ __forceinline__ v2f vfma(v2f a, v2f b, v2f c) {
    return __builtin_elementwise_fma(a, b, c);
}
__device__ __forceinline__ v2f sp(float x) { v2f r; r.x = x; r.y = x; return r; }

__device__ __forceinline__ float ssim1(float mu1, float mu2, float spp, float stt, float spt) {
    const float C1 = 1e-4f, C2 = 9e-4f;
    float mu1s = mu1 * mu1, mu2s = mu2 * mu2, mu12 = mu1 * mu2;
    float s1 = spp - mu1s, s2 = stt - mu2s, s12 = spt - mu12;
    float num = (2.f * mu12 + C1) * (2.f * s12 + C2);
    float den = (mu1s + mu2s + C1) * (s1 + s2 + C2);
    return num * __builtin_amdgcn_rcpf(den);
}

// H-first separable SSIM (R24 = R20 VERBATIM revert).
// R21-R23 (single-stall pair body) failed with a BIT-IDENTICAL absmax
// (0.203125) across three fence configurations including a full asm
// memory clobber -- proving a deterministic source-semantic bug in that
// rewrite, not an ordering race. Three strikes: experiment closed, revert
// to the last passing best (R20: 36.4us, absmax 0).
// Structure: pair processing (rows j, j+1 per iteration), shift-by-2
// 6-slot window, packed v2f math, 1 col/thread, single LDS row buffer per
// wave (same-wave DS is in-order; center read sw[lane+4] anchors the
// write->read order), two static prefetch generations, rolled 19-pair
// loop, no barriers.
template<int ATOMIC>
__global__ __launch_bounds__(256) void ssim_main(
    const float* __restrict__ pred,
    const float* __restrict__ targ,
    const float* __restrict__ window,
    float* __restrict__ wsum)
{
    __shared__ v2f sbuf[4][72];    // [wave][col c at idx c-X0+4] = (p,t)

    const int lane = threadIdx.x & 63;
    const int wid  = threadIdx.x >> 6;
    const int gw   = blockIdx.x * 4 + wid;   // 0..4095
    const int n    = gw >> 5;                // image
    const int r    = gw & 31;
    const int r0   = (r >> 2) * ROWS;        // strip start row (8 strips)
    const int X0   = (r & 3) << 6;           // col quarter: 0/64/128/192

    // exact 1D gaussian from w2d row 3 (exactly symmetric): g0..g3
    float g0, g1, g2, g3;
    {
        float w0 = window[21], w1 = window[22], w2 = window[23], w3 = window[24],
              w4 = window[25], w5 = window[26], w6 = window[27];
        float inv = 1.f / (((w0 + w6) + (w1 + w5)) + ((w2 + w4) + w3));
        g0 = w0 * inv; g1 = w1 * inv; g2 = w2 * inv; g3 = w3 * inv;
    }

    const float* pimg = pred + (size_t)n * (IMG_H * IMG_W);
    const float* timg = targ + (size_t)n * (IMG_H * IMG_W);
    const int mo = X0 + lane;         // own column

    // halo duty, lanes 0..5: left cols X0-3..X0-1 (idx 1..3),
    // right cols X0+64..X0+66 (idx 68..70)
    int hidx = 0, hcol = 0;
    if (lane < 3)      { hidx = lane + 1;  hcol = X0 - 3 + lane;  }
    else if (lane < 6) { hidx = lane + 65; hcol = X0 + 61 + lane; }
    const bool hv = (lane < 6) && ((unsigned)hcol < (unsigned)IMG_W);

    // 6-slot window: W[i] = H(row j-6+i) at pair start (j = first row of pair)
    v2f  Wmu[6], Wsq[6];
    float Wpt[6];
#pragma unroll
    for (int i = 0; i < 6; ++i) { Wmu[i] = sp(0.f); Wsq[i] = sp(0.f); Wpt[i] = 0.f; }
    float acc = 0.f;

    float PrA, TrA, PrB, TrB;   // two static prefetch generations
    v2f HrA, HrB;

#define GLOADX(J, PR, TR, HR) { \
    const int j_ = (J); \
    PR = 0.f; TR = 0.f; HR.x = 0.f; HR.y = 0.f; \
    if ((unsigned)j_ < (unsigned)IMG_H) { \
        const float* pr_ = pimg + j_ * IMG_W; \
        const float* tr_ = timg + j_ * IMG_W; \
        PR = pr_[mo]; TR = tr_[mo]; \
        if (hv) { HR.x = pr_[hcol]; HR.y = tr_[hcol]; } \
    } }

// stage (PR,TR,HR) as current LDS row, read 7-col neighborhood, H-conv
#define HALF(PR, TR, HR, HMU, HSQ, HPT) { \
    { v2f st_; st_.x = PR; st_.y = TR; sw[lane + 4] = st_; } \
    if (lane < 6) sw[hidx] = HR; \
    v2f q0 = sw[lane + 1], q1 = sw[lane + 2], q2 = sw[lane + 3]; \
    v2f q3 = sw[lane + 4], q4 = sw[lane + 5], q5 = sw[lane + 6]; \
    v2f q6 = sw[lane + 7]; \
    { \
        v2f a = q0 + q6, b = q1 + q5, c = q2 + q4; \
        HMU = vfma(sp(g0), a, vfma(sp(g1), b, vfma(sp(g2), c, sp(g3) * q3))); \
        v2f a2 = vfma(q6, q6, q0 * q0); \
        v2f b2 = vfma(q5, q5, q1 * q1); \
        v2f c2 = vfma(q4, q4, q2 * q2); \
        v2f d2 = q3 * q3; \
        HSQ = vfma(sp(g0), a2, vfma(sp(g1), b2, vfma(sp(g2), c2, sp(g3) * d2))); \
        float ap = fmaf(q6.x, q6.y, q0.x * q0.y); \
        float bp = fmaf(q5.x, q5.y, q1.x * q1.y); \
        float cp = fmaf(q4.x, q4.y, q2.x * q2.y); \
        HPT = fmaf(g0, ap, fmaf(g1, bp, fmaf(g2, cp, g3 * (q3.x * q3.y)))); \
    } }

    // prologue: prefetch rows r0-3 (A) and r0-2 (B)
    GLOADX(r0 - 3, PrA, TrA, HrA)
    GLOADX(r0 - 2, PrB, TrB, HrB)

    v2f* sw = sbuf[wid];

    v2f hmuA, hsqA, hmuB, hsqB;
    float hptA, hptB;

    // 19 pairs: rows (r0-3+2p, r0-2+2p); pairs 0..2 prologue (no output)
#pragma unroll 1
    for (int pp = 0; pp < 19; ++pp) {
        const int j = r0 - 3 + 2 * pp;

        // half A: row j; then prefetch row j+2 into the A set
        HALF(PrA, TrA, HrA, hmuA, hsqA, hptA)
        GLOADX(j + 2, PrA, TrA, HrA)

        // half B: row j+1; then prefetch row j+3 into the B set
        HALF(PrB, TrB, HrB, hmuB, hsqB, hptB)
        GLOADX(j + 3, PrB, TrB, HrB)

        if (pp >= 3) {
            // output row j-3: H rows j-6..j = W[0..5] + hA
            {
                v2f m12 = vfma(sp(g0), Wmu[0] + hmuA,
                          vfma(sp(g1), Wmu[1] + Wmu[5],
                          vfma(sp(g2), Wmu[2] + Wmu[4], sp(g3) * Wmu[3])));
                v2f s12 = vfma(sp(g0), Wsq[0] + hsqA,
                          vfma(sp(g1), Wsq[1] + Wsq[5],
                          vfma(sp(g2), Wsq[2] + Wsq[4], sp(g3) * Wsq[3])));
                float pt = fmaf(g0, Wpt[0] + hptA, fmaf(g1, Wpt[1] + Wpt[5],
                           fmaf(g2, Wpt[2] + Wpt[4], g3 * Wpt[3])));
                acc += ssim1(m12.x, m12.y, s12.x, s12.y, pt);
            }
            // output row j-2: H rows j-5..j+1 = W[1..5] + hA + hB
            {
                v2f m12 = vfma(sp(g0), Wmu[1] + hmuB,
                          vfma(sp(g1), Wmu[2] + hmuA,
                          vfma(sp(g2), Wmu[3] + Wmu[5], sp(g3) * Wmu[4])));
                v2f s12 = vfma(sp(g0), Wsq[1] + hsqB,
                          vfma(sp(g1), Wsq[2] + hsqA,
                          vfma(sp(g2), Wsq[3] + Wsq[5], sp(g3) * Wsq[4])));
                float pt = fmaf(g0, Wpt[1] + hptB, fmaf(g1, Wpt[2] + hptA,
                           fmaf(g2, Wpt[3] + Wpt[5], g3 * Wpt[4])));
                acc += ssim1(m12.x, m12.y, s12.x, s12.y, pt);
            }
        }

        // shift by 2 and insert the fresh pair (static indices)
        Wmu[0] = Wmu[2]; Wmu[1] = Wmu[3]; Wmu[2] = Wmu[4]; Wmu[3] = Wmu[5];
        Wmu[4] = hmuA;   Wmu[5] = hmuB;
        Wsq[0] = Wsq[2]; Wsq[1] = Wsq[3]; Wsq[2] = Wsq[4]; Wsq[3] = Wsq[5];
        Wsq[4] = hsqA;   Wsq[5] = hsqB;
        Wpt[0] = Wpt[2]; Wpt[1] = Wpt[3]; Wpt[2] = Wpt[4]; Wpt[3] = Wpt[5];
        Wpt[4] = hptA;   Wpt[5] = hptB;
    }

#undef GLOADX
#undef HALF

    // wave reduce, one write (or atomic) per wave
#pragma unroll
    for (int off = 32; off > 0; off >>= 1)
        acc += __shfl_xor(acc, off, 64);
    if (lane == 0) {
        if (ATOMIC) atomicAdd(&wsum[0], acc);
        else        wsum[gw] = acc;
    }
}

// deterministic f64 tree-reduce of the 4096 per-wave partials
__global__ __launch_bounds__(256) void ssim_final_arr(
    const float* __restrict__ ws, float* __restrict__ out)
{
    __shared__ double sred[4];
    double sm = 0.0;
#pragma unroll
    for (int k = 0; k < NWAVES / 256; ++k)
        sm += (double)ws[threadIdx.x + k * 256];
#pragma unroll
    for (int off = 32; off > 0; off >>= 1)
        sm += __shfl_down(sm, off, 64);
    const int lane = threadIdx.x & 63, wid = threadIdx.x >> 6;
    if (lane == 0) sred[wid] = sm;
    __syncthreads();
    if (threadIdx.x == 0) {
        double tot = sred[0] + sred[1] + sred[2] + sred[3];
        out[0] = (float)(1.0 - tot * (1.0 / (128.0 * 256.0 * 256.0)));
    }
}

__global__ void ssim_final_sc(const float* __restrict__ ws, float* __restrict__ out)
{
    out[0] = 1.0f - ws[0] * (1.0f / (128.0f * 256.0f * 256.0f));
}

extern "C" void kernel_launch(void* const* d_in, const int* in_sizes, int n_in,
                              void* d_out, int out_size, void* d_ws, size_t ws_size,
                              hipStream_t stream)
{
    const float* pred   = (const float*)d_in[0];
    const float* targ   = (const float*)d_in[1];
    const float* window = (const float*)d_in[2];
    float* out = (float*)d_out;
    float* ws  = (float*)d_ws;

    if (ws_size >= NWAVES * sizeof(float)) {
        // every ws slot is written by the grid each call: no memset needed
        ssim_main<0><<<NWAVES / 4, 256, 0, stream>>>(pred, targ, window, ws);
        ssim_final_arr<<<1, 256, 0, stream>>>(ws, out);
    } else {
        hipMemsetAsync(ws, 0, sizeof(float), stream);
        ssim_main<1><<<NWAVES / 4, 256, 0, stream>>>(pred, targ, window, ws);
        ssim_final_sc<<<1, 1, 0, stream>>>(ws, out);
    }
    (void)in_sizes; (void)n_in; (void)out_size;
}